// Round 11
// baseline (34.889 us; speedup 1.0000x reference)
//
#include <hip/hip_runtime.h>
#include <hip/hip_bf16.h>
#include <stdint.h>

typedef __bf16 bf16x8 __attribute__((ext_vector_type(8)));
typedef float f32x16 __attribute__((ext_vector_type(16)));
typedef float f32x4 __attribute__((ext_vector_type(4)));

__device__ __forceinline__ uint16_t f2bf(float f) {
    uint32_t u = __float_as_uint(f);
    u += 0x7FFFu + ((u >> 16) & 1u);   // RNE
    return (uint16_t)(u >> 16);
}

__device__ __forceinline__ uint32_t pack2bf(float g0, float g1) {
    __bf16 a = (__bf16)g0, b = (__bf16)g1;       // v_cvt_pk_bf16_f32
    uint16_t ua = __builtin_bit_cast(uint16_t, a);
    uint16_t ub = __builtin_bit_cast(uint16_t, b);
    return (uint32_t)ua | ((uint32_t)ub << 16);
}

__device__ __forceinline__ float bf2f(uint16_t u) {
    return __uint_as_float((uint32_t)u << 16);
}

__device__ __forceinline__ float gelu_tanh(float x) {
    float x2 = x * x;
    float t = fmaf(x2, 0.044715f, 1.0f);
    float e = __expf(1.5957691216057308f * x * t);
    return x - x * __fdividef(1.0f, e + 1.0f);
}

// per-pair scalar x = gamma*dist + beta (generic index form)
__device__ __forceinline__ float pair_x_bij(uint32_t b, uint32_t i, uint32_t jj, int N,
                                            const float* __restrict__ coord,
                                            const int* __restrict__ node_type,
                                            const float* __restrict__ gamma_emb,
                                            const float* __restrict__ beta_emb) {
    const float* ci = coord + ((size_t)b * N + i) * 3;
    const float* cj = coord + ((size_t)b * N + jj) * 3;
    float dx = ci[0] - cj[0];
    float dy = ci[1] - cj[1];
    float dz = ci[2] - cj[2];
    float dist = sqrtf(dx * dx + dy * dy + dz * dz);
    int nti = node_type[b * N + i];
    int ntj = node_type[b * N + jj];
    float g  = gamma_emb[nti + 2] + gamma_emb[ntj + 103];   // MAX_NODE_TYPE+3 = 103
    float be = beta_emb[nti + 2]  + beta_emb[ntj + 103];
    return fmaf(g, dist, be);
}

__device__ __forceinline__ float pair_x(uint32_t p, int N, uint32_t NN,
                                        const float* __restrict__ coord,
                                        const int* __restrict__ node_type,
                                        const float* __restrict__ gamma_emb,
                                        const float* __restrict__ beta_emb) {
    uint32_t b = p / NN;
    uint32_t rem = p - b * NN;
    uint32_t i = rem / (uint32_t)N;
    uint32_t jj = rem - i * (uint32_t)N;
    return pair_x_bij(b, i, jj, N, coord, node_type, gamma_emb, beta_emb);
}

// Kernel 1: analytic x-range (per-block redundant, deterministic) + build bf16 table.
// 512 blocks x 256 threads, 64 table rows per block (2 blocks/CU).
__global__ __launch_bounds__(256, 2)
void spenc_build_ab(const float* __restrict__ coord,
                    const int* __restrict__ node_type,
                    const float* __restrict__ gamma_emb,
                    const float* __restrict__ beta_emb,
                    const float* __restrict__ W1,
                    const float* __restrict__ b1,
                    const float* __restrict__ W2,
                    const float* __restrict__ b2,
                    const float* __restrict__ means,
                    const float* __restrict__ stds,
                    float* __restrict__ mmf,
                    uint16_t* __restrict__ tabb, int NTAB, int BN)
{
    __shared__ uint16_t AB[64 * 128];
    __shared__ uint16_t W1s[128 * 128];
    __shared__ uint16_t W2s[32 * 128];
    __shared__ float xs[64];
    __shared__ float rlo[4][7], rhi[4][7];

    const int tid = threadIdx.x;
    const int lane = tid & 63;
    const int w = tid >> 6;               // wave 0..3
    const uint32_t base = blockIdx.x * 64u;

    // ---- analytic bounds over nodes: bbox + per-type gamma/beta ranges ----
    {
        float lo[7], hi[7];
        #pragma unroll
        for (int q = 0; q < 7; ++q) { lo[q] = 3.4e38f; hi[q] = -3.4e38f; }
        for (int n = tid; n < BN; n += 256) {
            float v[7];
            v[0] = coord[n * 3 + 0];
            v[1] = coord[n * 3 + 1];
            v[2] = coord[n * 3 + 2];
            int nt = node_type[n];
            v[3] = gamma_emb[nt + 2];
            v[4] = gamma_emb[nt + 103];
            v[5] = beta_emb[nt + 2];
            v[6] = beta_emb[nt + 103];
            #pragma unroll
            for (int q = 0; q < 7; ++q) {
                lo[q] = fminf(lo[q], v[q]);
                hi[q] = fmaxf(hi[q], v[q]);
            }
        }
        #pragma unroll
        for (int m = 1; m < 64; m <<= 1) {
            #pragma unroll
            for (int q = 0; q < 7; ++q) {
                lo[q] = fminf(lo[q], __shfl_xor(lo[q], m));
                hi[q] = fmaxf(hi[q], __shfl_xor(hi[q], m));
            }
        }
        if (lane == 0) {
            #pragma unroll
            for (int q = 0; q < 7; ++q) { rlo[w][q] = lo[q]; rhi[w][q] = hi[q]; }
        }
    }

    // ---- stage W1/W2 f32 -> bf16 LDS (swizzled) ----
    {
        const float4* w1v = (const float4*)W1;
        #pragma unroll
        for (int it = 0; it < 8; ++it) {
            int idx = tid + it * 256;          // 2048 chunks of 8 elems
            int j = idx >> 4, c = idx & 15;
            float4 a = w1v[idx * 2];
            float4 b = w1v[idx * 2 + 1];
            uint4 v;
            v.x = pack2bf(a.x, a.y);
            v.y = pack2bf(a.z, a.w);
            v.z = pack2bf(b.x, b.y);
            v.w = pack2bf(b.z, b.w);
            int off = j * 256 + ((c * 16) ^ ((j & 15) << 4));
            *(uint4*)((char*)W1s + off) = v;
        }
        const float4* w2v = (const float4*)W2;
        #pragma unroll
        for (int it = 0; it < 2; ++it) {
            int idx = tid + it * 256;          // 512 chunks
            int j = idx >> 4, c = idx & 15;
            float4 a = w2v[idx * 2];
            float4 b = w2v[idx * 2 + 1];
            uint4 v;
            v.x = pack2bf(a.x, a.y);
            v.y = pack2bf(a.z, a.w);
            v.z = pack2bf(b.x, b.y);
            v.w = pack2bf(b.z, b.w);
            int off = j * 256 + ((c * 16) ^ ((j & 15) << 4));
            *(uint4*)((char*)W2s + off) = v;
        }
    }
    __syncthreads();

    // ---- combine bounds; interval-arithmetic x range (wave-uniform) ----
    float xmin, xmax;
    {
        float lo[7], hi[7];
        #pragma unroll
        for (int q = 0; q < 7; ++q) { lo[q] = rlo[0][q]; hi[q] = rhi[0][q]; }
        #pragma unroll
        for (int i = 1; i < 4; ++i) {
            #pragma unroll
            for (int q = 0; q < 7; ++q) {
                lo[q] = fminf(lo[q], rlo[i][q]);
                hi[q] = fmaxf(hi[q], rhi[i][q]);
            }
        }
        float dx = hi[0] - lo[0], dy = hi[1] - lo[1], dz = hi[2] - lo[2];
        float dmax = sqrtf(dx * dx + dy * dy + dz * dz);
        float glo = lo[3] + lo[4], ghi = hi[3] + hi[4];
        float blo = lo[5] + lo[6], bhi = hi[5] + hi[6];
        float plo = fminf(0.0f, fminf(glo * dmax, ghi * dmax));
        float phi = fmaxf(0.0f, fmaxf(glo * dmax, ghi * dmax));
        xmin = plo + blo;
        xmax = phi + bhi;
    }
    if (blockIdx.x == 0 && tid == 0) { mmf[0] = xmin; mmf[1] = xmax; }

    if (tid < 64) {
        float dxg = fmaxf(xmax - xmin, 1e-6f) / (float)(NTAB - 1);
        xs[tid] = fmaf((float)(base + tid), dxg, xmin);
    }
    __syncthreads();

    // ---- gaussian basis -> bf16 tile (params computed inline) ----
    {
        const int kp = tid & 63;
        const int rgrp = tid >> 6;            // 0..3
        const int k0 = kp * 2;
        const float mm0 = means[k0], mm1 = means[k0 + 1];
        const float s0 = fabsf(stds[k0]) + 0.01f;
        const float s1 = fabsf(stds[k0 + 1]) + 0.01f;
        const float i0 = 1.0f / s0, i1 = 1.0f / s1;
        const float n0 = 0.3989422804014327f * i0;
        const float n1 = 0.3989422804014327f * i1;
        #pragma unroll
        for (int i = 0; i < 16; ++i) {
            int r = rgrp + (i << 2);          // 0..63
            float x = xs[r];
            float z0 = (x - mm0) * i0;
            float z1 = (x - mm1) * i1;
            float g0 = __expf(-0.5f * z0 * z0) * n0;
            float g1 = __expf(-0.5f * z1 * z1) * n1;
            int off = r * 256 + ((kp * 4) ^ ((r & 15) << 4));
            *(uint32_t*)((char*)AB + off) = pack2bf(g0, g1);
        }
    }
    __syncthreads();

    // ---- GEMM1 + gelu ----
    const int mb = w >> 1;                    // 0..1 (rows mb*32..+31)
    const int nb = w & 1;                     // 0..1 (cols nb*64..+63)
    const int l31 = lane & 31;
    const int hi2 = lane >> 5;

    f32x16 acc0, acc1;
    {
        float bia0 = b1[nb * 64 + l31];
        float bia1 = b1[nb * 64 + 32 + l31];
        #pragma unroll
        for (int r = 0; r < 16; ++r) { acc0[r] = bia0; acc1[r] = bia1; }
    }
    const int arow = mb * 32 + l31;
    const int aswz = (arow & 15) << 4;
    const int jcol0 = nb * 64 + l31;
    const int jcol1 = nb * 64 + 32 + l31;
    const int jswz0 = (jcol0 & 15) << 4;
    const int jswz1 = (jcol1 & 15) << 4;
    #pragma unroll
    for (int kk = 0; kk < 8; ++kk) {
        int koff = kk * 32 + 16 * hi2;
        bf16x8 a  = *(const bf16x8*)((const char*)AB  + arow  * 256 + (koff ^ aswz));
        bf16x8 b0 = *(const bf16x8*)((const char*)W1s + jcol0 * 256 + (koff ^ jswz0));
        bf16x8 b1f= *(const bf16x8*)((const char*)W1s + jcol1 * 256 + (koff ^ jswz1));
        acc0 = __builtin_amdgcn_mfma_f32_32x32x16_bf16(a, b0,  acc0, 0, 0, 0);
        acc1 = __builtin_amdgcn_mfma_f32_32x32x16_bf16(a, b1f, acc1, 0, 0, 0);
    }
    __syncthreads();

    #pragma unroll
    for (int r = 0; r < 16; ++r) {
        int row = mb * 32 + (r & 3) + 8 * (r >> 2) + 4 * hi2;   // 0..63
        int rowoff = row * 256 + ((row & 15) << 4);
        float h0 = gelu_tanh(acc0[r]);
        float h1 = gelu_tanh(acc1[r]);
        *(__bf16*)((char*)AB + (rowoff ^ (2 * jcol0))) = (__bf16)h0;
        *(__bf16*)((char*)AB + (rowoff ^ (2 * jcol1))) = (__bf16)h1;
    }
    __syncthreads();

    // ---- GEMM2 -> bf16 table (waves 0..1) ----
    if (w < 2) {
        f32x16 acc2;
        float bia = b2[l31];
        #pragma unroll
        for (int r = 0; r < 16; ++r) acc2[r] = bia;
        const int hrow = w * 32 + l31;
        const int hswz = (hrow & 15) << 4;
        const int hcol = l31;
        const int hcswz = (hcol & 15) << 4;
        #pragma unroll
        for (int kk = 0; kk < 8; ++kk) {
            int koff = kk * 32 + 16 * hi2;
            bf16x8 a  = *(const bf16x8*)((const char*)AB  + hrow * 256 + (koff ^ hswz));
            bf16x8 bb = *(const bf16x8*)((const char*)W2s + hcol * 256 + (koff ^ hcswz));
            acc2 = __builtin_amdgcn_mfma_f32_32x32x16_bf16(a, bb, acc2, 0, 0, 0);
        }
        #pragma unroll
        for (int r = 0; r < 16; ++r) {
            int row = w * 32 + (r & 3) + 8 * (r >> 2) + 4 * hi2;
            tabb[((size_t)(base + row)) * 32 + hcol] = f2bf(acc2[r]);
        }
    }
}

// Kernel 2 (fast path, N % 64 == 0): 3D grid — zero integer divides.
// grid = (N/64, N, batch); 4 threads/pair; PLAIN stores (nt removed — A/B).
__global__ __launch_bounds__(256)
void spenc_interp3d(const float* __restrict__ coord,
                    const int* __restrict__ node_type,
                    const float* __restrict__ gamma_emb,
                    const float* __restrict__ beta_emb,
                    const float* __restrict__ mmf,
                    const uint16_t* __restrict__ tabb,
                    float* __restrict__ out,
                    int N, int NTAB)
{
    const int tid = threadIdx.x;
    const uint32_t b = blockIdx.z;
    const uint32_t i = blockIdx.y;
    const uint32_t j = blockIdx.x * 64u + (tid >> 2);
    const int sub = tid & 3;              // heads sub*8 .. sub*8+7

    const uint32_t rowbase = b * (uint32_t)N + i;     // node index of source i

    // row-uniform (blockIdx-only) values
    const float* ci = coord + (size_t)rowbase * 3;
    const float cix = ci[0], ciy = ci[1], ciz = ci[2];
    const int nti = node_type[rowbase];
    const float gi = gamma_emb[nti + 2];
    const float bi = beta_emb[nti + 2];

    // per-pair values
    const uint32_t jnode = b * (uint32_t)N + j;
    const float* cj = coord + (size_t)jnode * 3;
    float dx = cix - cj[0];
    float dy = ciy - cj[1];
    float dz = ciz - cj[2];
    float dist = sqrtf(dx * dx + dy * dy + dz * dz);
    int ntj = node_type[jnode];
    float g  = gi + gamma_emb[ntj + 103];
    float be = bi + beta_emb[ntj + 103];
    float x = fmaf(g, dist, be);

    float xmin = mmf[0], xmax = mmf[1];
    float inv_dx = (float)(NTAB - 1) / fmaxf(xmax - xmin, 1e-6f);

    float u = (x - xmin) * inv_dx;
    u = fminf(fmaxf(u, 0.0f), (float)(NTAB - 1) - 0.001f);
    int i0 = (int)u;
    float f = u - (float)i0;

    const uint4* ra = (const uint4*)(tabb + (size_t)i0 * 32) + sub;
    uint4 av = ra[0];
    uint4 bv = ra[4];     // next table row (+64 B)

    const ushort* au = (const ushort*)&av;
    const ushort* bu = (const ushort*)&bv;
    float o[8];
    #pragma unroll
    for (int t = 0; t < 8; ++t) {
        float a = bf2f(au[t]);
        float bb = bf2f(bu[t]);
        o[t] = fmaf(f, bb - a, a);
    }
    size_t p = (size_t)rowbase * (size_t)N + j;
    f32x4* dst = (f32x4*)(out + p * 32 + sub * 8);
    f32x4 v0 = {o[0], o[1], o[2], o[3]};
    f32x4 v1 = {o[4], o[5], o[6], o[7]};
    dst[0] = v0;
    dst[1] = v1;
}

// Kernel 2 (generic path): 1D grid with divides.
__global__ __launch_bounds__(256)
void spenc_interp(const float* __restrict__ coord,
                  const int* __restrict__ node_type,
                  const float* __restrict__ gamma_emb,
                  const float* __restrict__ beta_emb,
                  const float* __restrict__ mmf,
                  const uint16_t* __restrict__ tabb,
                  float* __restrict__ out,
                  int N, uint32_t NN, uint32_t M, int NTAB)
{
    const int tid = threadIdx.x;
    const uint32_t base = blockIdx.x * 64u;
    const uint32_t p = base + (tid >> 2);
    if (p >= M) return;
    const int sub = tid & 3;

    float x = pair_x(p, N, NN, coord, node_type, gamma_emb, beta_emb);

    float xmin = mmf[0], xmax = mmf[1];
    float inv_dx = (float)(NTAB - 1) / fmaxf(xmax - xmin, 1e-6f);

    float u = (x - xmin) * inv_dx;
    u = fminf(fmaxf(u, 0.0f), (float)(NTAB - 1) - 0.001f);
    int i0 = (int)u;
    float f = u - (float)i0;

    const uint4* ra = (const uint4*)(tabb + (size_t)i0 * 32) + sub;
    uint4 av = ra[0];
    uint4 bv = ra[4];

    const ushort* au = (const ushort*)&av;
    const ushort* bu = (const ushort*)&bv;
    float o[8];
    #pragma unroll
    for (int t = 0; t < 8; ++t) {
        float a = bf2f(au[t]);
        float bb = bf2f(bu[t]);
        o[t] = fmaf(f, bb - a, a);
    }
    f32x4* dst = (f32x4*)(out + (size_t)p * 32 + sub * 8);
    f32x4 v0 = {o[0], o[1], o[2], o[3]};
    f32x4 v1 = {o[4], o[5], o[6], o[7]};
    dst[0] = v0;
    dst[1] = v1;
}

// Standalone prep (fallback path only).
__global__ void spenc_prep(const float* __restrict__ W1, const float* __restrict__ W2,
                           const float* __restrict__ means, const float* __restrict__ stds,
                           uint16_t* __restrict__ w1b, uint16_t* __restrict__ w2b,
                           float* __restrict__ prm)
{
    int idx = blockIdx.x * 256 + threadIdx.x;
    if (idx < 16384) w1b[idx] = f2bf(W1[idx]);
    if (idx < 4096)  w2b[idx] = f2bf(W2[idx]);
    if (idx < 128) {
        float s = fabsf(stds[idx]) + 0.01f;
        prm[idx]       = means[idx];
        prm[128 + idx] = 1.0f / s;
        prm[256 + idx] = 0.3989422804014327f / s;
    }
}

// Fallback (round-3 direct kernel) if ws can't hold the table.
__global__ __launch_bounds__(512, 4)
void spenc_main(const float* __restrict__ coord,
                const int* __restrict__ node_type,
                const float* __restrict__ gamma_emb,
                const float* __restrict__ beta_emb,
                const float* __restrict__ b1,
                const float* __restrict__ b2,
                const uint16_t* __restrict__ w1b,
                const uint16_t* __restrict__ w2b,
                const float* __restrict__ prm,
                float* __restrict__ out,
                int N)
{
    __shared__ uint16_t AB[128 * 128];
    __shared__ uint16_t W1s[128 * 128];
    __shared__ uint16_t W2s[32 * 128];
    __shared__ float sprm[384];
    __shared__ float xs[128];

    const int tid = threadIdx.x;
    const int lane = tid & 63;
    const int w = tid >> 6;
    const uint32_t NN = (uint32_t)N * (uint32_t)N;
    const uint32_t base = blockIdx.x * 128u;

    #pragma unroll
    for (int it = 0; it < 4; ++it) {
        int idx = tid + it * 512;
        int j = idx >> 4, c = idx & 15;
        uint4 v = ((const uint4*)w1b)[idx];
        int off = j * 256 + ((c * 16) ^ ((j & 15) << 4));
        *(uint4*)((char*)W1s + off) = v;
    }
    {
        int j = tid >> 4, c = tid & 15;
        uint4 v = ((const uint4*)w2b)[tid];
        int off = j * 256 + ((c * 16) ^ ((j & 15) << 4));
        *(uint4*)((char*)W2s + off) = v;
    }
    if (tid < 384) sprm[tid] = prm[tid];
    if (tid < 128) xs[tid] = pair_x(base + tid, N, NN, coord, node_type, gamma_emb, beta_emb);
    __syncthreads();

    {
        const int kp = tid & 63;
        const int rgrp = tid >> 6;
        const int k0 = kp * 2;
        const float m0 = sprm[k0],       m1 = sprm[k0 + 1];
        const float i0 = sprm[128 + k0], i1 = sprm[128 + k0 + 1];
        const float n0 = sprm[256 + k0], n1 = sprm[256 + k0 + 1];
        #pragma unroll
        for (int i = 0; i < 16; ++i) {
            int r = rgrp + (i << 3);
            float x = xs[r];
            float z0 = (x - m0) * i0;
            float z1 = (x - m1) * i1;
            float g0 = __expf(-0.5f * z0 * z0) * n0;
            float g1 = __expf(-0.5f * z1 * z1) * n1;
            int off = r * 256 + ((kp * 4) ^ ((r & 15) << 4));
            *(uint32_t*)((char*)AB + off) = pack2bf(g0, g1);
        }
    }
    __syncthreads();

    const int mb = w >> 1;
    const int nb = w & 1;
    const int l31 = lane & 31;
    const int hi = lane >> 5;

    f32x16 acc0, acc1;
    {
        float bia0 = b1[nb * 64 + l31];
        float bia1 = b1[nb * 64 + 32 + l31];
        #pragma unroll
        for (int r = 0; r < 16; ++r) { acc0[r] = bia0; acc1[r] = bia1; }
    }
    const int arow = mb * 32 + l31;
    const int aswz = (arow & 15) << 4;
    const int jcol0 = nb * 64 + l31;
    const int jcol1 = nb * 64 + 32 + l31;
    const int jswz0 = (jcol0 & 15) << 4;
    const int jswz1 = (jcol1 & 15) << 4;
    #pragma unroll
    for (int kk = 0; kk < 8; ++kk) {
        int koff = kk * 32 + 16 * hi;
        bf16x8 a  = *(const bf16x8*)((const char*)AB  + arow  * 256 + (koff ^ aswz));
        bf16x8 b0 = *(const bf16x8*)((const char*)W1s + jcol0 * 256 + (koff ^ jswz0));
        bf16x8 b1f= *(const bf16x8*)((const char*)W1s + jcol1 * 256 + (koff ^ jswz1));
        acc0 = __builtin_amdgcn_mfma_f32_32x32x16_bf16(a, b0,  acc0, 0, 0, 0);
        acc1 = __builtin_amdgcn_mfma_f32_32x32x16_bf16(a, b1f, acc1, 0, 0, 0);
    }
    __syncthreads();

    #pragma unroll
    for (int r = 0; r < 16; ++r) {
        int row = mb * 32 + (r & 3) + 8 * (r >> 2) + 4 * hi;
        int rowoff = row * 256 + ((row & 15) << 4);
        float h0 = gelu_tanh(acc0[r]);
        float h1 = gelu_tanh(acc1[r]);
        *(__bf16*)((char*)AB + (rowoff ^ (2 * jcol0))) = (__bf16)h0;
        *(__bf16*)((char*)AB + (rowoff ^ (2 * jcol1))) = (__bf16)h1;
    }
    __syncthreads();

    if (w < 4) {
        f32x16 acc2;
        float bia = b2[l31];
        #pragma unroll
        for (int r = 0; r < 16; ++r) acc2[r] = bia;
        const int hrow = w * 32 + l31;
        const int hswz = (hrow & 15) << 4;
        const int hcol = l31;
        const int hcswz = (hcol & 15) << 4;
        #pragma unroll
        for (int kk = 0; kk < 8; ++kk) {
            int koff = kk * 32 + 16 * hi;
            bf16x8 a  = *(const bf16x8*)((const char*)AB  + hrow * 256 + (koff ^ hswz));
            bf16x8 bb = *(const bf16x8*)((const char*)W2s + hcol * 256 + (koff ^ hcswz));
            acc2 = __builtin_amdgcn_mfma_f32_32x32x16_bf16(a, bb, acc2, 0, 0, 0);
        }
        #pragma unroll
        for (int r = 0; r < 16; ++r) {
            int row = w * 32 + (r & 3) + 8 * (r >> 2) + 4 * hi;
            out[((size_t)(base + row)) * 32 + hcol] = acc2[r];
        }
    }
}

extern "C" void kernel_launch(void* const* d_in, const int* in_sizes, int n_in,
                              void* d_out, int out_size, void* d_ws, size_t ws_size,
                              hipStream_t stream)
{
    const float* coord     = (const float*)d_in[0];
    const int*   node_type = (const int*)d_in[1];
    const float* means     = (const float*)d_in[2];
    const float* stds      = (const float*)d_in[3];
    const float* W1        = (const float*)d_in[4];
    const float* b1        = (const float*)d_in[5];
    const float* W2        = (const float*)d_in[6];
    const float* b2        = (const float*)d_in[7];
    const float* gamma_emb = (const float*)d_in[8];
    const float* beta_emb  = (const float*)d_in[9];
    float* out = (float*)d_out;

    int BN = in_sizes[1];                                   // b*N
    uint32_t M = (uint32_t)((long long)out_size / 32);      // b*N*N pairs
    int N = (int)(M / (uint32_t)BN);                        // 512
    uint32_t NN = (uint32_t)N * (uint32_t)N;
    int batch = BN / N;                                     // 2

    uint16_t* w1b = (uint16_t*)d_ws;                        // 32 KB @ 0 (fallback only)
    uint16_t* w2b = w1b + 16384;                            // 8 KB
    float* prm = (float*)(w2b + 4096);                      // 1.5 KB
    float* mmf = (float*)((char*)d_ws + 43008);             // 8 B
    uint16_t* tabb = (uint16_t*)((char*)d_ws + 65536);      // bf16 table

    // 32768 entries: 2.1 MiB table fits a single XCD's 4 MiB L2.
    int NTAB = 0;
    if (ws_size >= 65536 + (size_t)32768 * 64) NTAB = 32768;

    if (NTAB) {
        spenc_build_ab<<<NTAB / 64, 256, 0, stream>>>(coord, node_type, gamma_emb,
                                                      beta_emb, W1, b1, W2, b2,
                                                      means, stds, mmf, tabb, NTAB, BN);
        if ((N % 64) == 0 && batch * N == BN) {
            dim3 grid(N / 64, N, batch);
            spenc_interp3d<<<grid, 256, 0, stream>>>(coord, node_type, gamma_emb,
                                                     beta_emb, mmf, tabb, out, N, NTAB);
        } else {
            spenc_interp<<<(M + 63) / 64, 256, 0, stream>>>(coord, node_type, gamma_emb,
                                                            beta_emb, mmf, tabb, out,
                                                            N, NN, M, NTAB);
        }
    } else {
        spenc_prep<<<64, 256, 0, stream>>>(W1, W2, means, stds, w1b, w2b, prm);
        spenc_main<<<M / 128, 512, 0, stream>>>(coord, node_type, gamma_emb, beta_emb,
                                                b1, b2, w1b, w2b, prm, out, N);
    }
}

// Round 12
// 30.930 us; speedup vs baseline: 1.1280x; 1.1280x over previous
//
#include <hip/hip_runtime.h>
#include <hip/hip_bf16.h>
#include <stdint.h>

typedef __bf16 bf16x8 __attribute__((ext_vector_type(8)));
typedef float f32x16 __attribute__((ext_vector_type(16)));
typedef float f32x4 __attribute__((ext_vector_type(4)));

__device__ __forceinline__ uint16_t f2bf(float f) {
    uint32_t u = __float_as_uint(f);
    u += 0x7FFFu + ((u >> 16) & 1u);   // RNE
    return (uint16_t)(u >> 16);
}

__device__ __forceinline__ uint32_t pack2bf(float g0, float g1) {
    __bf16 a = (__bf16)g0, b = (__bf16)g1;       // v_cvt_pk_bf16_f32
    uint16_t ua = __builtin_bit_cast(uint16_t, a);
    uint16_t ub = __builtin_bit_cast(uint16_t, b);
    return (uint32_t)ua | ((uint32_t)ub << 16);
}

__device__ __forceinline__ float bf2f(uint16_t u) {
    return __uint_as_float((uint32_t)u << 16);
}

__device__ __forceinline__ float gelu_tanh(float x) {
    float x2 = x * x;
    float t = fmaf(x2, 0.044715f, 1.0f);
    float e = __expf(1.5957691216057308f * x * t);
    return x - x * __fdividef(1.0f, e + 1.0f);
}

// per-pair scalar x = gamma*dist + beta (generic index form)
__device__ __forceinline__ float pair_x_bij(uint32_t b, uint32_t i, uint32_t jj, int N,
                                            const float* __restrict__ coord,
                                            const int* __restrict__ node_type,
                                            const float* __restrict__ gamma_emb,
                                            const float* __restrict__ beta_emb) {
    const float* ci = coord + ((size_t)b * N + i) * 3;
    const float* cj = coord + ((size_t)b * N + jj) * 3;
    float dx = ci[0] - cj[0];
    float dy = ci[1] - cj[1];
    float dz = ci[2] - cj[2];
    float dist = sqrtf(dx * dx + dy * dy + dz * dz);
    int nti = node_type[b * N + i];
    int ntj = node_type[b * N + jj];
    float g  = gamma_emb[nti + 2] + gamma_emb[ntj + 103];   // MAX_NODE_TYPE+3 = 103
    float be = beta_emb[nti + 2]  + beta_emb[ntj + 103];
    return fmaf(g, dist, be);
}

__device__ __forceinline__ float pair_x(uint32_t p, int N, uint32_t NN,
                                        const float* __restrict__ coord,
                                        const int* __restrict__ node_type,
                                        const float* __restrict__ gamma_emb,
                                        const float* __restrict__ beta_emb) {
    uint32_t b = p / NN;
    uint32_t rem = p - b * NN;
    uint32_t i = rem / (uint32_t)N;
    uint32_t jj = rem - i * (uint32_t)N;
    return pair_x_bij(b, i, jj, N, coord, node_type, gamma_emb, beta_emb);
}

// Kernel 1: analytic x-range (per-block redundant, deterministic) + build bf16 table.
// 256 blocks x 512 threads, 128 table rows per block (round-9 best config).
__global__ __launch_bounds__(512, 4)
void spenc_build_ab(const float* __restrict__ coord,
                    const int* __restrict__ node_type,
                    const float* __restrict__ gamma_emb,
                    const float* __restrict__ beta_emb,
                    const float* __restrict__ W1,
                    const float* __restrict__ b1,
                    const float* __restrict__ W2,
                    const float* __restrict__ b2,
                    const float* __restrict__ means,
                    const float* __restrict__ stds,
                    float* __restrict__ mmf,
                    uint16_t* __restrict__ tabb, int NTAB, int BN)
{
    __shared__ uint16_t AB[128 * 128];
    __shared__ uint16_t W1s[128 * 128];
    __shared__ uint16_t W2s[32 * 128];
    __shared__ float xs[128];
    __shared__ float rlo[8][7], rhi[8][7];

    const int tid = threadIdx.x;
    const int lane = tid & 63;
    const int w = tid >> 6;
    const uint32_t base = blockIdx.x * 128u;

    // ---- analytic bounds over nodes: bbox + per-type gamma/beta ranges ----
    {
        float lo[7], hi[7];
        #pragma unroll
        for (int q = 0; q < 7; ++q) { lo[q] = 3.4e38f; hi[q] = -3.4e38f; }
        for (int n = tid; n < BN; n += 512) {
            float v[7];
            v[0] = coord[n * 3 + 0];
            v[1] = coord[n * 3 + 1];
            v[2] = coord[n * 3 + 2];
            int nt = node_type[n];
            v[3] = gamma_emb[nt + 2];
            v[4] = gamma_emb[nt + 103];
            v[5] = beta_emb[nt + 2];
            v[6] = beta_emb[nt + 103];
            #pragma unroll
            for (int q = 0; q < 7; ++q) {
                lo[q] = fminf(lo[q], v[q]);
                hi[q] = fmaxf(hi[q], v[q]);
            }
        }
        #pragma unroll
        for (int m = 1; m < 64; m <<= 1) {
            #pragma unroll
            for (int q = 0; q < 7; ++q) {
                lo[q] = fminf(lo[q], __shfl_xor(lo[q], m));
                hi[q] = fmaxf(hi[q], __shfl_xor(hi[q], m));
            }
        }
        if (lane == 0) {
            #pragma unroll
            for (int q = 0; q < 7; ++q) { rlo[w][q] = lo[q]; rhi[w][q] = hi[q]; }
        }
    }

    // ---- stage W1/W2 f32 -> bf16 LDS (swizzled) ----
    {
        const float4* w1v = (const float4*)W1;
        #pragma unroll
        for (int it = 0; it < 4; ++it) {
            int idx = tid + it * 512;          // 2048 chunks of 8 elems
            int j = idx >> 4, c = idx & 15;
            float4 a = w1v[idx * 2];
            float4 b = w1v[idx * 2 + 1];
            uint4 v;
            v.x = pack2bf(a.x, a.y);
            v.y = pack2bf(a.z, a.w);
            v.z = pack2bf(b.x, b.y);
            v.w = pack2bf(b.z, b.w);
            int off = j * 256 + ((c * 16) ^ ((j & 15) << 4));
            *(uint4*)((char*)W1s + off) = v;
        }
        const float4* w2v = (const float4*)W2;
        {
            int j = tid >> 4, c = tid & 15;    // 512 chunks
            float4 a = w2v[tid * 2];
            float4 b = w2v[tid * 2 + 1];
            uint4 v;
            v.x = pack2bf(a.x, a.y);
            v.y = pack2bf(a.z, a.w);
            v.z = pack2bf(b.x, b.y);
            v.w = pack2bf(b.z, b.w);
            int off = j * 256 + ((c * 16) ^ ((j & 15) << 4));
            *(uint4*)((char*)W2s + off) = v;
        }
    }
    __syncthreads();

    // ---- combine bounds; interval-arithmetic x range (wave-uniform) ----
    float xmin, xmax;
    {
        float lo[7], hi[7];
        #pragma unroll
        for (int q = 0; q < 7; ++q) { lo[q] = rlo[0][q]; hi[q] = rhi[0][q]; }
        #pragma unroll
        for (int i = 1; i < 8; ++i) {
            #pragma unroll
            for (int q = 0; q < 7; ++q) {
                lo[q] = fminf(lo[q], rlo[i][q]);
                hi[q] = fmaxf(hi[q], rhi[i][q]);
            }
        }
        float dx = hi[0] - lo[0], dy = hi[1] - lo[1], dz = hi[2] - lo[2];
        float dmax = sqrtf(dx * dx + dy * dy + dz * dz);
        float glo = lo[3] + lo[4], ghi = hi[3] + hi[4];
        float blo = lo[5] + lo[6], bhi = hi[5] + hi[6];
        float plo = fminf(0.0f, fminf(glo * dmax, ghi * dmax));
        float phi = fmaxf(0.0f, fmaxf(glo * dmax, ghi * dmax));
        xmin = plo + blo;
        xmax = phi + bhi;
    }
    if (blockIdx.x == 0 && tid == 0) { mmf[0] = xmin; mmf[1] = xmax; }

    if (tid < 128) {
        float dxg = fmaxf(xmax - xmin, 1e-6f) / (float)(NTAB - 1);
        xs[tid] = fmaf((float)(base + tid), dxg, xmin);
    }
    __syncthreads();

    // ---- gaussian basis -> bf16 tile (params computed inline) ----
    {
        const int kp = tid & 63;
        const int rgrp = tid >> 6;
        const int k0 = kp * 2;
        const float mm0 = means[k0], mm1 = means[k0 + 1];
        const float s0 = fabsf(stds[k0]) + 0.01f;
        const float s1 = fabsf(stds[k0 + 1]) + 0.01f;
        const float i0 = 1.0f / s0, i1 = 1.0f / s1;
        const float n0 = 0.3989422804014327f * i0;
        const float n1 = 0.3989422804014327f * i1;
        #pragma unroll
        for (int i = 0; i < 16; ++i) {
            int r = rgrp + (i << 3);
            float x = xs[r];
            float z0 = (x - mm0) * i0;
            float z1 = (x - mm1) * i1;
            float g0 = __expf(-0.5f * z0 * z0) * n0;
            float g1 = __expf(-0.5f * z1 * z1) * n1;
            int off = r * 256 + ((kp * 4) ^ ((r & 15) << 4));
            *(uint32_t*)((char*)AB + off) = pack2bf(g0, g1);
        }
    }
    __syncthreads();

    // ---- GEMM1 + gelu ----
    const int mb = w >> 1;
    const int nb = w & 1;
    const int l31 = lane & 31;
    const int hi2 = lane >> 5;

    f32x16 acc0, acc1;
    {
        float bia0 = b1[nb * 64 + l31];
        float bia1 = b1[nb * 64 + 32 + l31];
        #pragma unroll
        for (int r = 0; r < 16; ++r) { acc0[r] = bia0; acc1[r] = bia1; }
    }
    const int arow = mb * 32 + l31;
    const int aswz = (arow & 15) << 4;
    const int jcol0 = nb * 64 + l31;
    const int jcol1 = nb * 64 + 32 + l31;
    const int jswz0 = (jcol0 & 15) << 4;
    const int jswz1 = (jcol1 & 15) << 4;
    #pragma unroll
    for (int kk = 0; kk < 8; ++kk) {
        int koff = kk * 32 + 16 * hi2;
        bf16x8 a  = *(const bf16x8*)((const char*)AB  + arow  * 256 + (koff ^ aswz));
        bf16x8 b0 = *(const bf16x8*)((const char*)W1s + jcol0 * 256 + (koff ^ jswz0));
        bf16x8 b1f= *(const bf16x8*)((const char*)W1s + jcol1 * 256 + (koff ^ jswz1));
        acc0 = __builtin_amdgcn_mfma_f32_32x32x16_bf16(a, b0,  acc0, 0, 0, 0);
        acc1 = __builtin_amdgcn_mfma_f32_32x32x16_bf16(a, b1f, acc1, 0, 0, 0);
    }
    __syncthreads();

    #pragma unroll
    for (int r = 0; r < 16; ++r) {
        int row = mb * 32 + (r & 3) + 8 * (r >> 2) + 4 * hi2;
        int rowoff = row * 256 + ((row & 15) << 4);
        float h0 = gelu_tanh(acc0[r]);
        float h1 = gelu_tanh(acc1[r]);
        *(__bf16*)((char*)AB + (rowoff ^ (2 * jcol0))) = (__bf16)h0;
        *(__bf16*)((char*)AB + (rowoff ^ (2 * jcol1))) = (__bf16)h1;
    }
    __syncthreads();

    // ---- GEMM2 -> bf16 table ----
    if (w < 4) {
        f32x16 acc2;
        float bia = b2[l31];
        #pragma unroll
        for (int r = 0; r < 16; ++r) acc2[r] = bia;
        const int hrow = w * 32 + l31;
        const int hswz = (hrow & 15) << 4;
        const int hcol = l31;
        const int hcswz = (hcol & 15) << 4;
        #pragma unroll
        for (int kk = 0; kk < 8; ++kk) {
            int koff = kk * 32 + 16 * hi2;
            bf16x8 a  = *(const bf16x8*)((const char*)AB  + hrow * 256 + (koff ^ hswz));
            bf16x8 bb = *(const bf16x8*)((const char*)W2s + hcol * 256 + (koff ^ hcswz));
            acc2 = __builtin_amdgcn_mfma_f32_32x32x16_bf16(a, bb, acc2, 0, 0, 0);
        }
        #pragma unroll
        for (int r = 0; r < 16; ++r) {
            int row = w * 32 + (r & 3) + 8 * (r >> 2) + 4 * hi2;
            tabb[((size_t)(base + row)) * 32 + hcol] = f2bf(acc2[r]);
        }
    }
}

// Kernel 2 (fast path, N % 32 == 0): 3D grid, 8 threads/pair, 32 pairs/block.
// Each thread: 2 x 8B table reads, 4 lerps, ONE 16B nt store -> a wave's store
// instruction covers 64 x 16B = 1024B fully contiguous (8 pairs x 128B).
__global__ __launch_bounds__(256)
void spenc_interp3d(const float* __restrict__ coord,
                    const int* __restrict__ node_type,
                    const float* __restrict__ gamma_emb,
                    const float* __restrict__ beta_emb,
                    const float* __restrict__ mmf,
                    const uint16_t* __restrict__ tabb,
                    float* __restrict__ out,
                    int N, int NTAB)
{
    const int tid = threadIdx.x;
    const uint32_t b = blockIdx.z;
    const uint32_t i = blockIdx.y;
    const uint32_t j = blockIdx.x * 32u + (tid >> 3);
    const int c = tid & 7;                 // 16B chunk within the 128B pair row

    const uint32_t rowbase = b * (uint32_t)N + i;

    // row-uniform (blockIdx-only) values
    const float* ci = coord + (size_t)rowbase * 3;
    const float cix = ci[0], ciy = ci[1], ciz = ci[2];
    const int nti = node_type[rowbase];
    const float gi = gamma_emb[nti + 2];
    const float bi = beta_emb[nti + 2];

    // per-pair values (computed redundantly by the 8 threads of a pair)
    const uint32_t jnode = b * (uint32_t)N + j;
    const float* cj = coord + (size_t)jnode * 3;
    float dx = cix - cj[0];
    float dy = ciy - cj[1];
    float dz = ciz - cj[2];
    float dist = sqrtf(dx * dx + dy * dy + dz * dz);
    int ntj = node_type[jnode];
    float g  = gi + gamma_emb[ntj + 103];
    float be = bi + beta_emb[ntj + 103];
    float x = fmaf(g, dist, be);

    float xmin = mmf[0], xmax = mmf[1];
    float inv_dx = (float)(NTAB - 1) / fmaxf(xmax - xmin, 1e-6f);

    float u = (x - xmin) * inv_dx;
    u = fminf(fmaxf(u, 0.0f), (float)(NTAB - 1) - 0.001f);
    int i0 = (int)u;
    float f = u - (float)i0;

    // this thread's 4 heads: c*4 .. c*4+3  -> 8B slice of each 64B table row
    const uint2* ra = (const uint2*)(tabb + (size_t)i0 * 32) + c;
    uint2 av = ra[0];
    uint2 bv = ra[8];     // next table row (+64 B = 8 uint2)

    const ushort* au = (const ushort*)&av;
    const ushort* bu = (const ushort*)&bv;
    float o[4];
    #pragma unroll
    for (int t = 0; t < 4; ++t) {
        float a = bf2f(au[t]);
        float bb = bf2f(bu[t]);
        o[t] = fmaf(f, bb - a, a);
    }
    size_t p = (size_t)rowbase * (size_t)N + j;
    f32x4* dst = (f32x4*)(out + p * 32 + c * 4);
    f32x4 v0 = {o[0], o[1], o[2], o[3]};
    __builtin_nontemporal_store(v0, dst);
}

// Kernel 2 (generic path): 1D grid with divides, 8 threads/pair.
__global__ __launch_bounds__(256)
void spenc_interp(const float* __restrict__ coord,
                  const int* __restrict__ node_type,
                  const float* __restrict__ gamma_emb,
                  const float* __restrict__ beta_emb,
                  const float* __restrict__ mmf,
                  const uint16_t* __restrict__ tabb,
                  float* __restrict__ out,
                  int N, uint32_t NN, uint32_t M, int NTAB)
{
    const int tid = threadIdx.x;
    const uint32_t p = blockIdx.x * 32u + (tid >> 3);
    if (p >= M) return;
    const int c = tid & 7;

    float x = pair_x(p, N, NN, coord, node_type, gamma_emb, beta_emb);

    float xmin = mmf[0], xmax = mmf[1];
    float inv_dx = (float)(NTAB - 1) / fmaxf(xmax - xmin, 1e-6f);

    float u = (x - xmin) * inv_dx;
    u = fminf(fmaxf(u, 0.0f), (float)(NTAB - 1) - 0.001f);
    int i0 = (int)u;
    float f = u - (float)i0;

    const uint2* ra = (const uint2*)(tabb + (size_t)i0 * 32) + c;
    uint2 av = ra[0];
    uint2 bv = ra[8];

    const ushort* au = (const ushort*)&av;
    const ushort* bu = (const ushort*)&bv;
    float o[4];
    #pragma unroll
    for (int t = 0; t < 4; ++t) {
        float a = bf2f(au[t]);
        float bb = bf2f(bu[t]);
        o[t] = fmaf(f, bb - a, a);
    }
    f32x4* dst = (f32x4*)(out + (size_t)p * 32 + c * 4);
    f32x4 v0 = {o[0], o[1], o[2], o[3]};
    __builtin_nontemporal_store(v0, dst);
}

// Standalone prep (fallback path only).
__global__ void spenc_prep(const float* __restrict__ W1, const float* __restrict__ W2,
                           const float* __restrict__ means, const float* __restrict__ stds,
                           uint16_t* __restrict__ w1b, uint16_t* __restrict__ w2b,
                           float* __restrict__ prm)
{
    int idx = blockIdx.x * 256 + threadIdx.x;
    if (idx < 16384) w1b[idx] = f2bf(W1[idx]);
    if (idx < 4096)  w2b[idx] = f2bf(W2[idx]);
    if (idx < 128) {
        float s = fabsf(stds[idx]) + 0.01f;
        prm[idx]       = means[idx];
        prm[128 + idx] = 1.0f / s;
        prm[256 + idx] = 0.3989422804014327f / s;
    }
}

// Fallback (round-3 direct kernel) if ws can't hold the table.
__global__ __launch_bounds__(512, 4)
void spenc_main(const float* __restrict__ coord,
                const int* __restrict__ node_type,
                const float* __restrict__ gamma_emb,
                const float* __restrict__ beta_emb,
                const float* __restrict__ b1,
                const float* __restrict__ b2,
                const uint16_t* __restrict__ w1b,
                const uint16_t* __restrict__ w2b,
                const float* __restrict__ prm,
                float* __restrict__ out,
                int N)
{
    __shared__ uint16_t AB[128 * 128];
    __shared__ uint16_t W1s[128 * 128];
    __shared__ uint16_t W2s[32 * 128];
    __shared__ float sprm[384];
    __shared__ float xs[128];

    const int tid = threadIdx.x;
    const int lane = tid & 63;
    const int w = tid >> 6;
    const uint32_t NN = (uint32_t)N * (uint32_t)N;
    const uint32_t base = blockIdx.x * 128u;

    #pragma unroll
    for (int it = 0; it < 4; ++it) {
        int idx = tid + it * 512;
        int j = idx >> 4, c = idx & 15;
        uint4 v = ((const uint4*)w1b)[idx];
        int off = j * 256 + ((c * 16) ^ ((j & 15) << 4));
        *(uint4*)((char*)W1s + off) = v;
    }
    {
        int j = tid >> 4, c = tid & 15;
        uint4 v = ((const uint4*)w2b)[tid];
        int off = j * 256 + ((c * 16) ^ ((j & 15) << 4));
        *(uint4*)((char*)W2s + off) = v;
    }
    if (tid < 384) sprm[tid] = prm[tid];
    if (tid < 128) xs[tid] = pair_x(base + tid, N, NN, coord, node_type, gamma_emb, beta_emb);
    __syncthreads();

    {
        const int kp = tid & 63;
        const int rgrp = tid >> 6;
        const int k0 = kp * 2;
        const float m0 = sprm[k0],       m1 = sprm[k0 + 1];
        const float i0 = sprm[128 + k0], i1 = sprm[128 + k0 + 1];
        const float n0 = sprm[256 + k0], n1 = sprm[256 + k0 + 1];
        #pragma unroll
        for (int i = 0; i < 16; ++i) {
            int r = rgrp + (i << 3);
            float x = xs[r];
            float z0 = (x - m0) * i0;
            float z1 = (x - m1) * i1;
            float g0 = __expf(-0.5f * z0 * z0) * n0;
            float g1 = __expf(-0.5f * z1 * z1) * n1;
            int off = r * 256 + ((kp * 4) ^ ((r & 15) << 4));
            *(uint32_t*)((char*)AB + off) = pack2bf(g0, g1);
        }
    }
    __syncthreads();

    const int mb = w >> 1;
    const int nb = w & 1;
    const int l31 = lane & 31;
    const int hi = lane >> 5;

    f32x16 acc0, acc1;
    {
        float bia0 = b1[nb * 64 + l31];
        float bia1 = b1[nb * 64 + 32 + l31];
        #pragma unroll
        for (int r = 0; r < 16; ++r) { acc0[r] = bia0; acc1[r] = bia1; }
    }
    const int arow = mb * 32 + l31;
    const int aswz = (arow & 15) << 4;
    const int jcol0 = nb * 64 + l31;
    const int jcol1 = nb * 64 + 32 + l31;
    const int jswz0 = (jcol0 & 15) << 4;
    const int jswz1 = (jcol1 & 15) << 4;
    #pragma unroll
    for (int kk = 0; kk < 8; ++kk) {
        int koff = kk * 32 + 16 * hi;
        bf16x8 a  = *(const bf16x8*)((const char*)AB  + arow  * 256 + (koff ^ aswz));
        bf16x8 b0 = *(const bf16x8*)((const char*)W1s + jcol0 * 256 + (koff ^ jswz0));
        bf16x8 b1f= *(const bf16x8*)((const char*)W1s + jcol1 * 256 + (koff ^ jswz1));
        acc0 = __builtin_amdgcn_mfma_f32_32x32x16_bf16(a, b0,  acc0, 0, 0, 0);
        acc1 = __builtin_amdgcn_mfma_f32_32x32x16_bf16(a, b1f, acc1, 0, 0, 0);
    }
    __syncthreads();

    #pragma unroll
    for (int r = 0; r < 16; ++r) {
        int row = mb * 32 + (r & 3) + 8 * (r >> 2) + 4 * hi;
        int rowoff = row * 256 + ((row & 15) << 4);
        float h0 = gelu_tanh(acc0[r]);
        float h1 = gelu_tanh(acc1[r]);
        *(__bf16*)((char*)AB + (rowoff ^ (2 * jcol0))) = (__bf16)h0;
        *(__bf16*)((char*)AB + (rowoff ^ (2 * jcol1))) = (__bf16)h1;
    }
    __syncthreads();

    if (w < 4) {
        f32x16 acc2;
        float bia = b2[l31];
        #pragma unroll
        for (int r = 0; r < 16; ++r) acc2[r] = bia;
        const int hrow = w * 32 + l31;
        const int hswz = (hrow & 15) << 4;
        const int hcol = l31;
        const int hcswz = (hcol & 15) << 4;
        #pragma unroll
        for (int kk = 0; kk < 8; ++kk) {
            int koff = kk * 32 + 16 * hi;
            bf16x8 a  = *(const bf16x8*)((const char*)AB  + hrow * 256 + (koff ^ hswz));
            bf16x8 bb = *(const bf16x8*)((const char*)W2s + hcol * 256 + (koff ^ hcswz));
            acc2 = __builtin_amdgcn_mfma_f32_32x32x16_bf16(a, bb, acc2, 0, 0, 0);
        }
        #pragma unroll
        for (int r = 0; r < 16; ++r) {
            int row = w * 32 + (r & 3) + 8 * (r >> 2) + 4 * hi;
            out[((size_t)(base + row)) * 32 + hcol] = acc2[r];
        }
    }
}

extern "C" void kernel_launch(void* const* d_in, const int* in_sizes, int n_in,
                              void* d_out, int out_size, void* d_ws, size_t ws_size,
                              hipStream_t stream)
{
    const float* coord     = (const float*)d_in[0];
    const int*   node_type = (const int*)d_in[1];
    const float* means     = (const float*)d_in[2];
    const float* stds      = (const float*)d_in[3];
    const float* W1        = (const float*)d_in[4];
    const float* b1        = (const float*)d_in[5];
    const float* W2        = (const float*)d_in[6];
    const float* b2        = (const float*)d_in[7];
    const float* gamma_emb = (const float*)d_in[8];
    const float* beta_emb  = (const float*)d_in[9];
    float* out = (float*)d_out;

    int BN = in_sizes[1];                                   // b*N
    uint32_t M = (uint32_t)((long long)out_size / 32);      // b*N*N pairs
    int N = (int)(M / (uint32_t)BN);                        // 512
    uint32_t NN = (uint32_t)N * (uint32_t)N;
    int batch = BN / N;                                     // 2

    uint16_t* w1b = (uint16_t*)d_ws;                        // 32 KB @ 0 (fallback only)
    uint16_t* w2b = w1b + 16384;                            // 8 KB
    float* prm = (float*)(w2b + 4096);                      // 1.5 KB
    float* mmf = (float*)((char*)d_ws + 43008);             // 8 B
    uint16_t* tabb = (uint16_t*)((char*)d_ws + 65536);      // bf16 table

    // 32768 entries: 2.1 MiB table fits a single XCD's 4 MiB L2.
    int NTAB = 0;
    if (ws_size >= 65536 + (size_t)32768 * 64) NTAB = 32768;

    if (NTAB) {
        spenc_build_ab<<<NTAB / 128, 512, 0, stream>>>(coord, node_type, gamma_emb,
                                                       beta_emb, W1, b1, W2, b2,
                                                       means, stds, mmf, tabb, NTAB, BN);
        if ((N % 32) == 0 && batch * N == BN) {
            dim3 grid(N / 32, N, batch);
            spenc_interp3d<<<grid, 256, 0, stream>>>(coord, node_type, gamma_emb,
                                                     beta_emb, mmf, tabb, out, N, NTAB);
        } else {
            spenc_interp<<<(M + 31) / 32, 256, 0, stream>>>(coord, node_type, gamma_emb,
                                                            beta_emb, mmf, tabb, out,
                                                            N, NN, M, NTAB);
        }
    } else {
        spenc_prep<<<64, 256, 0, stream>>>(W1, W2, means, stds, w1b, w2b, prm);
        spenc_main<<<M / 128, 512, 0, stream>>>(coord, node_type, gamma_emb, beta_emb,
                                                b1, b2, w1b, w2b, prm, out, N);
    }
}